// Round 9
// baseline (247.889 us; speedup 1.0000x reference)
//
#include <hip/hip_runtime.h>
#include <hip/hip_fp16.h>

// ColorDeformConv2d — round 13: barrier-free k-loop, direct-from-L2 B frags.
// vs r12 (LDS-staged, ~60 barriers, 150us, barrier tuning null): the staged
// B layout is a pure pass-through of the cg-interleaved fused2 layout — each
// wave can load its MFMA B-fragment DIRECTLY from global (16B/lane, two 512B
// segments/wave, L2-resident ~48KB working set). So: no Bst, no staging
// barriers; waves run independently through the whole U-GEMM. pm GEMM rides
// free in pass 0 on waves 0/1 (they already hold bf0/bf1; ks ascending ->
// bit-identical). Barriers/block: ~60 -> 11. LDS keeps only Amod(16K,
// uL overlay) + tables.
//
// ws (u16 elems): A_c[20mt][36ks][64l][8] @0 (368640), A_pm @368640 (18432),
// A_conv[2][40][64][8] @387072 (40960), Wcd row-major @428032 (8192),
// fused2 @436224 (4*64*16384, cg-interleaved). Total 9.3 MB.
//
// k3 LDS (27904 B, 4 blocks/CU): R@0 16K (Amod; uL 6.9K overlay in pm->tables
// window) | sidx@16384 2304 | w4h@18688 4608 | mL@23296 2304 | bcL@25600 2304

typedef __attribute__((ext_vector_type(8))) __bf16 bf16x8;
typedef __attribute__((ext_vector_type(16))) float f32x16;
#define MFMA32(a, b, c) __builtin_amdgcn_mfma_f32_32x32x16_bf16((a), (b), (c), 0, 0, 0)

#define WS_AC    0
#define WS_APM   368640
#define WS_ACONV 387072
#define WS_WCD   428032
#define WS_F2    436224

struct f2pair { float x, y; };              // align 4: legal 4B-aligned dwordx2

__device__ __forceinline__ unsigned short f2bf(float f) {
    unsigned u = __float_as_uint(f);
    return (unsigned short)((u + 0x7FFFu + ((u >> 16) & 1u)) >> 16);   // RNE
}
__device__ __forceinline__ float fast_rcp(float x) {
#if __has_builtin(__builtin_amdgcn_rcpf)
    return __builtin_amdgcn_rcpf(x);
#else
    return 1.0f / x;
#endif
}
__device__ __forceinline__ float fast_tanh(float x) {
    float t = __expf(2.0f * x);
    return 1.0f - 2.0f * fast_rcp(t + 1.0f);
}
__device__ __forceinline__ float fast_sigmoid(float x) {
    return fast_rcp(1.0f + __expf(-x));
}

// ---------------- prep: weight repack to frag-order bf16 (unchanged) --------
__global__ void prep_kernel(const float* __restrict__ w_c, const float* __restrict__ w_p,
                            const float* __restrict__ w_m, const float* __restrict__ w_conv,
                            const float* __restrict__ w_cd, unsigned short* __restrict__ ws) {
    int i = blockIdx.x * 256 + threadIdx.x;
    if (i >= 436224) return;
    float val;
    if (i < WS_APM) {                       // A_c: row=gmt*32+(l&31), k'=ks*16+(l>>5)*8+j
        int t = i, j = t & 7, l = (t >> 3) & 63, r = t >> 9, ks = r % 36, gmt = r / 36;
        int row = gmt * 32 + (l & 31);
        int kp = ks * 16 + (l >> 5) * 8 + j, tap = kp >> 6, ci = kp & 63;
        val = (row < 576) ? w_c[row * 576 + ci * 9 + tap] : 0.0f;
    } else if (i < WS_ACONV) {              // A_pm: rows 0-17 w_p, 18-26 w_m
        int t = i - WS_APM, j = t & 7, l = (t >> 3) & 63, ks = t >> 9;
        int row = l & 31;
        int kp = ks * 16 + (l >> 5) * 8 + j, tap = kp >> 6, ci = kp & 63;
        val = (row < 18) ? w_p[row * 576 + ci * 9 + tap]
            : (row < 27) ? w_m[(row - 18) * 576 + ci * 9 + tap] : 0.0f;
    } else if (i < WS_WCD) {                // A_conv: k = U-row (natural order)
        int t = i - WS_ACONV, j = t & 7, l = (t >> 3) & 63, r = t >> 9;
        int gks = r % 40, ocT = r / 40;
        int oc = ocT * 32 + (l & 31);
        int krow = gks * 16 + (l >> 5) * 8 + j;
        val = (krow < 576) ? w_conv[oc * 576 + krow] : 0.0f;
    } else {                                // Wcd row-major [64][128]
        val = w_cd[i - WS_WCD];
    }
    ws[i] = f2bf(val);
}

// ------ direct B-fragment load from cg-interleaved fused2 (16B/lane) --------
__device__ __forceinline__ uint4 loadB4(const unsigned short* f2b, int hs,
                                        int wsrc, int cg) {
    uint4 pk = {0u, 0u, 0u, 0u};
    if (((unsigned)hs < 128u) && ((unsigned)wsrc < 128u))
        pk = *(const uint4*)(f2b + (((size_t)cg << 14) + (hs << 7) + wsrc) * 8);
    return pk;
}

// ---------------- k2: fused 1x1 conv -> fused2 cg-interleaved (unchanged) ----
__global__ __launch_bounds__(256, 4)
void k2_fused(const float* __restrict__ x, const float* __restrict__ ref,
              const float* __restrict__ b_cd, const unsigned short* __restrict__ wsbf,
              unsigned short* __restrict__ ws) {
    __shared__ __align__(16) char B0[32768];
    const int tid = threadIdx.x, l = tid & 63, w = tid >> 6;
    const int b = blockIdx.y, p0 = blockIdx.x * 128;
    const int rl31 = l & 31, kh8 = (l >> 5) * 8;

    #pragma unroll
    for (int it = 0; it < 8; ++it) {        // 2048 tasks: kg(16) x px(128)
        int task = it * 256 + tid;
        int kg = task >> 7, px = task & 127;
        const float* src = (kg < 8) ? x : ref;
        int kbase = (kg & 7) * 8;
        unsigned short v[8];
        #pragma unroll
        for (int j = 0; j < 8; ++j)
            v[j] = f2bf(src[(((size_t)b * 64 + kbase + j) << 14) + p0 + px]);
        uint4 pk;
        pk.x = (unsigned)v[0] | ((unsigned)v[1] << 16);
        pk.y = (unsigned)v[2] | ((unsigned)v[3] << 16);
        pk.z = (unsigned)v[4] | ((unsigned)v[5] << 16);
        pk.w = (unsigned)v[6] | ((unsigned)v[7] << 16);
        *(uint4*)(B0 + ((kg >> 1) * 4 + (px >> 5)) * 1024
                      + ((px & 31) + 32 * (kg & 1)) * 16) = pk;
    }
    __syncthreads();

    f32x16 a0, a1;
    #pragma unroll
    for (int r = 0; r < 16; ++r) { a0[r] = 0.0f; a1[r] = 0.0f; }
    const unsigned short* A0 = wsbf + WS_WCD + rl31 * 128 + kh8;
    #pragma unroll
    for (int s = 0; s < 8; ++s) {
        bf16x8 bf = *(bf16x8*)(B0 + ((s * 4 + w) * 64 + l) * 16);
        bf16x8 x0 = *(const bf16x8*)(A0 + s * 16);
        bf16x8 x1 = *(const bf16x8*)(A0 + 32 * 128 + s * 16);
        a0 = MFMA32(x0, bf, a0);
        a1 = MFMA32(x1, bf, a1);
    }
    unsigned short* f2 = ws + WS_F2 + ((size_t)b << 20);
    int px = p0 + w * 32 + rl31;
    int h4 = (l >> 5) * 4;
    #pragma unroll
    for (int t = 0; t < 2; ++t)
        #pragma unroll
        for (int q = 0; q < 4; ++q) {
            ushort4 st;
            float v0 = (t ? a1[q * 4 + 0] : a0[q * 4 + 0]) + b_cd[t * 32 + 8 * q + h4 + 0];
            float v1 = (t ? a1[q * 4 + 1] : a0[q * 4 + 1]) + b_cd[t * 32 + 8 * q + h4 + 1];
            float v2 = (t ? a1[q * 4 + 2] : a0[q * 4 + 2]) + b_cd[t * 32 + 8 * q + h4 + 2];
            float v3 = (t ? a1[q * 4 + 3] : a0[q * 4 + 3]) + b_cd[t * 32 + 8 * q + h4 + 3];
            st.x = f2bf(v0); st.y = f2bf(v1); st.z = f2bf(v2); st.w = f2bf(v3);
            *(ushort4*)(f2 + ((size_t)((t * 4 + q) << 14) + px) * 8 + h4) = st;
        }
}

// ---------------- k3: barrier-free U-GEMM, direct-global B, 5 m-passes ------
__global__ __launch_bounds__(256, 4)
void k3_main(const float* __restrict__ x, const float* __restrict__ b_c,
             const float* __restrict__ b_p, const float* __restrict__ b_m,
             const unsigned short* __restrict__ wsbf, float* __restrict__ out) {
    __shared__ __align__(16) char lds[27904];
    char* R = lds;                          // 16K: Amod; uL overlay
    float* uL = (float*)lds;                // 6912B, live pm-end..tables-end
    short* sidx = (short*)(lds + 16384);
    unsigned short* w4h = (unsigned short*)(lds + 18688);
    float* mL = (float*)(lds + 23296);
    float* bcL = (float*)(lds + 25600);

    const int tid = threadIdx.x, l = tid & 63, w = tid >> 6;   // 4 waves
    const int lh = l >> 5, l31 = l & 31;
    // XCD-banded decode: xcd = id&7 owns h band [xcd*16, xcd*16+16) x b x half
    const int id = blockIdx.x;
    const int hbLin = (id & 7) * 128 + (id >> 3);
    const int half = hbLin & 1, b = (hbLin >> 1) & 3, h = hbLin >> 3;
    const int px0 = half * 64;
    const unsigned short* f2b = wsbf + WS_F2 + ((size_t)b << 20);

    for (int i = tid; i < 576; i += 256) bcL[i] = b_c[i];

    f32x16 oa;
    #pragma unroll
    for (int r = 0; r < 16; ++r) oa[r] = 0.0f;
    const float* xb = x + (((size_t)b * 64) << 14);
    const int ocT = w >> 1, nT2 = w & 1;

    #pragma unroll 1
    for (int p = 0; p < 5; ++p) {
        const int mt = p * 4 + w;           // exact 20 m-tiles over 5x4 waves
        const bool dopm = (p == 0) && (w < 2);
        f32x16 acc0, acc1, pm;
        #pragma unroll
        for (int r = 0; r < 16; ++r) { acc0[r] = 0.0f; acc1[r] = 0.0f; pm[r] = 0.0f; }

        // ---- U-GEMM k-loop: NO barriers, NO LDS; direct L2 loads ----
        const unsigned short* Abase = wsbf + WS_AC + (((size_t)mt * 36) * 64 + l) * 8;
        #pragma unroll 4
        for (int ks = 0; ks < 36; ++ks) {
            int tap = ks >> 2;
            int dh = tap / 3 - 1, dw = tap % 3 - 1;
            int hs = h + dh;
            int cg = ((ks & 3) << 1) + lh;
            int w0c = px0 + l31 + dw;
            uint4 pk0 = loadB4(f2b, hs, w0c, cg);
            uint4 pk1 = loadB4(f2b, hs, w0c + 32, cg);
            bf16x8 bf0 = *(bf16x8*)&pk0;
            bf16x8 bf1 = *(bf16x8*)&pk1;
            bf16x8 af = *(const bf16x8*)(Abase + (size_t)ks * 512);
            acc0 = MFMA32(af, bf0, acc0);
            acc1 = MFMA32(af, bf1, acc1);
            if (dopm) {                     // pass-0 free ride: pm GEMM
                bf16x8 apm = *(const bf16x8*)(wsbf + WS_APM + ((ks * 64 + l) << 3));
                pm = MFMA32(apm, w ? bf1 : bf0, pm);
            }
        }

        if (p == 0) {
            if (w < 2) {                    // pm -> uL (f32), nt = w
                int pxp = w * 32 + l31;
                #pragma unroll
                for (int reg = 0; reg < 16; ++reg) {
                    int rl = (reg & 3) + 8 * (reg >> 2) + 4 * lh;
                    uL[rl * 64 + pxp] = pm[reg];
                }
            }
            __syncthreads();
            // ---- tables from uL: pair-based bilinear (once per block) ----
            #pragma unroll 1
            for (int i = tid; i < 576; i += 256) {
                int n = i >> 6, px = i & 63;
                float offr = uL[n * 64 + px] + b_p[n];
                float offc = uL[(9 + n) * 64 + px] + b_p[9 + n];
                float mraw = uL[(18 + n) * 64 + px] + b_m[n];
                int nr = n / 3, nc = n - nr * 3;
                float pr = (float)(h + nr) + offr;
                float pc = (float)(px0 + px + nc) + offc;
                float flr = floorf(pr), flc = floorf(pc);
                float prc = fminf(fmaxf(pr, 0.0f), 129.0f);
                float pcc = fminf(fmaxf(pc, 0.0f), 129.0f);
                float q0r = fminf(fmaxf(flr, 0.0f), 129.0f);
                float q1r = fminf(fmaxf(flr + 1.0f, 0.0f), 129.0f);
                int ir0 = (int)q0r, ir1 = (int)q1r;
                bool vr0 = (ir0 >= 1) && (ir0 <= 128), vr1 = (ir1 >= 1) && (ir1 <= 128);
                float wr0 = vr0 ? (1.0f + q0r - prc) : 0.0f;
                float wr1 = vr1 ? (1.0f - (q1r - prc)) : 0.0f;
                float q0c = fminf(fmaxf(flc, 0.0f), 129.0f);
                float q1c = fminf(fmaxf(flc + 1.0f, 0.0f), 129.0f);
                int ic0 = (int)q0c, ic1 = (int)q1c;
                bool vc0 = (ic0 >= 1) && (ic0 <= 128), vc1 = (ic1 >= 1) && (ic1 <= 128);
                float wc0 = vc0 ? (1.0f + q0c - pcc) : 0.0f;
                float wc1 = vc1 ? (1.0f - (q1c - pcc)) : 0.0f;
                int cx0 = ic0 - 1, cx1 = ic1 - 1;
                int base = min(max(cx0, 0), 126);
                float ws0 = ((base == cx0) && vc0 ? wc0 : 0.0f)
                          + ((base == cx1) && vc1 ? wc1 : 0.0f);
                float ws1 = ((base + 1 == cx0) && vc0 ? wc0 : 0.0f)
                          + ((base + 1 == cx1) && vc1 ? wc1 : 0.0f);
                int rx0 = min(max(ir0 - 1, 0), 127), rx1 = min(max(ir1 - 1, 0), 127);
                short2 s2;
                s2.x = (short)(rx0 * 128 + base);
                s2.y = (short)(rx1 * 128 + base);
                ((short2*)sidx)[px * 9 + n] = s2;
                int wb = (px * 9 + n) * 4;
                w4h[wb + 0] = __half_as_ushort(__float2half(wr0 * ws0));
                w4h[wb + 1] = __half_as_ushort(__float2half(wr0 * ws1));
                w4h[wb + 2] = __half_as_ushort(__float2half(wr1 * ws0));
                w4h[wb + 3] = __half_as_ushort(__float2half(wr1 * ws1));
                mL[n * 64 + px] = fast_sigmoid(mraw);
            }
            __syncthreads();
        }

        // ---- epilogue: tanh + pair-load bilinear + modulate (in regs) ----
        const int rowbase = mt * 32;
        auto epi = [&](f32x16& a, int j) {
            const int pxe = j * 32 + l31;
            if (rowbase < 576) {
                #pragma unroll
                for (int reg = 0; reg < 16; ++reg) {
                    int rl = (reg & 3) + 8 * (reg >> 2) + 4 * lh;
                    int row = rowbase + rl;
                    int c = row / 9, n = row - c * 9;
                    float uv = a[reg] + bcL[row];
                    float t = fast_tanh(uv);
                    short2 s2 = ((short2*)sidx)[pxe * 9 + n];
                    int wb = (pxe * 9 + n) * 4;
                    uint2 wv = *(const uint2*)(w4h + wb);       // one b64 LDS read
                    float w0 = __half2float(__ushort_as_half((unsigned short)(wv.x & 0xffffu)));
                    float w1 = __half2float(__ushort_as_half((unsigned short)(wv.x >> 16)));
                    float w2 = __half2float(__ushort_as_half((unsigned short)(wv.y & 0xffffu)));
                    float w3 = __half2float(__ushort_as_half((unsigned short)(wv.y >> 16)));
                    const float* xp = xb + ((size_t)c << 14);
                    f2pair v0 = *(const f2pair*)(xp + s2.x);
                    f2pair v1 = *(const f2pair*)(xp + s2.y);
                    float samp = w0 * v0.x + w1 * v0.y + w2 * v1.x + w3 * v1.y;
                    a[reg] = mL[n * 64 + pxe] * (samp + t);
                    // bound gather clustering: <=8 loads in flight
                    if ((reg & 3) == 3) __builtin_amdgcn_sched_barrier(0);
                }
            } else {
                #pragma unroll
                for (int reg = 0; reg < 16; ++reg) a[reg] = 0.0f;
            }
        };
        epi(acc0, 0);
        epi(acc1, 1);

        // ---- scatter 128 rows -> Amod (=R), then out-GEMM accumulate ----
        if (p > 0) __syncthreads();         // prev pass's out-GEMM reads done
        auto scat = [&](const f32x16& a, int j) {
            #pragma unroll
            for (int reg = 0; reg < 16; ++reg) {
                int rl = (reg & 3) + 8 * (reg >> 2) + 4 * lh;
                int k = w * 32 + rl;        // pass-local row in [0,128)
                *(unsigned short*)(R + ((k >> 4) * 2 + j) * 1024
                        + (l31 + 32 * ((k >> 3) & 1)) * 16 + (k & 7) * 2)
                    = f2bf(a[reg]);
            }
        };
        scat(acc0, 0);
        scat(acc1, 1);
        __syncthreads();
        #pragma unroll
        for (int ks8 = 0; ks8 < 8; ++ks8) {
            bf16x8 af = *(const bf16x8*)(wsbf + WS_ACONV
                            + (((ocT * 40 + p * 8 + ks8) * 64 + l) << 3));
            bf16x8 bf = *(bf16x8*)(R + (ks8 * 2 + nT2) * 1024 + l * 16);
            oa = MFMA32(af, bf, oa);
        }
    }

    // ---- final store: each out element written exactly once ----
    float* ob = out + (((size_t)b * 64) << 14) + (h << 7) + px0 + nT2 * 32 + l31;
    #pragma unroll
    for (int reg = 0; reg < 16; ++reg) {
        int rl = (reg & 3) + 8 * (reg >> 2) + 4 * lh;
        int oc = ocT * 32 + rl;
        ob[(size_t)oc << 14] = oa[reg];
    }
}

extern "C" void kernel_launch(void* const* d_in, const int* in_sizes, int n_in,
                              void* d_out, int out_size, void* d_ws, size_t ws_size,
                              hipStream_t stream) {
    const float* x      = (const float*)d_in[0];
    const float* ref    = (const float*)d_in[1];
    const float* w_cd   = (const float*)d_in[2];
    const float* b_cd   = (const float*)d_in[3];
    const float* w_p    = (const float*)d_in[4];
    const float* b_p    = (const float*)d_in[5];
    const float* w_m    = (const float*)d_in[6];
    const float* b_m    = (const float*)d_in[7];
    const float* w_c    = (const float*)d_in[8];
    const float* b_c    = (const float*)d_in[9];
    const float* w_conv = (const float*)d_in[10];
    float* out = (float*)d_out;
    unsigned short* wsbf = (unsigned short*)d_ws;

    hipLaunchKernelGGL(prep_kernel, dim3(1704), dim3(256), 0, stream,
                       w_c, w_p, w_m, w_conv, w_cd, wsbf);
    hipLaunchKernelGGL(k2_fused, dim3(128, 4), dim3(256), 0, stream,
                       x, ref, b_cd, wsbf, wsbf);
    hipLaunchKernelGGL(k3_main, dim3(1024), dim3(256), 0, stream,
                       x, b_c, b_p, b_m, wsbf, out);
}

// Round 10
// 233.622 us; speedup vs baseline: 1.0611x; 1.0611x over previous
//
#include <hip/hip_runtime.h>
#include <hip/hip_fp16.h>

// ColorDeformConv2d — round 14: r11 k-loop (best measured, 143us) + 3 cuts.
// Ledger: r11 staged/1-chunk=143 | r12 2-chunk+prefetch=150 | r13 direct-L2=164
// -> staged 1-chunk dbuf is the k-loop optimum; this round cuts work, not
// structure: (1) pm GEMM folded into pass 0 (waves 0/1, +1 MFMA/ks on staged
// bf) -> 18-iter pre-phase deleted (17% of staged iters); oa init deferred so
// peak acc stays 48 in the k-loop. (2) packed 16B table record {4xhalf w,
// 2xu16 idx, f32 m}: 1 ds_read_b128 replaces 3 LDS reads/element; same bytes,
// same values. (3) prep merged into k2 (grid-stride slice + per-block Wcd->LDS)
// -> 2 launches instead of 3.
//
// ws (u16 elems): A_c[20mt][36ks][64l][8] @0 (368640), A_pm @368640 (18432),
// A_conv[2][40][64][8] @387072 (40960), fused2 @436224 (4*64*16384,
// cg-interleaved). (428032..436224 unused now.)
//
// k3 LDS (36096 B, 4 blocks/CU): Bst0@0 4K | Bst1@4096 4K | Amod@8192 16K
// (uL 6.9K overlay, dead after tables) | tbl@24576 9216 | bcL@33792 2304

typedef __attribute__((ext_vector_type(8))) __bf16 bf16x8;
typedef __attribute__((ext_vector_type(16))) float f32x16;
#define MFMA32(a, b, c) __builtin_amdgcn_mfma_f32_32x32x16_bf16((a), (b), (c), 0, 0, 0)

#define WS_AC    0
#define WS_APM   368640
#define WS_ACONV 387072
#define WS_F2    436224

struct f2pair { float x, y; };              // align 4: legal 4B-aligned dwordx2

__device__ __forceinline__ unsigned short f2bf(float f) {
    unsigned u = __float_as_uint(f);
    return (unsigned short)((u + 0x7FFFu + ((u >> 16) & 1u)) >> 16);   // RNE
}
__device__ __forceinline__ float fast_rcp(float x) {
#if __has_builtin(__builtin_amdgcn_rcpf)
    return __builtin_amdgcn_rcpf(x);
#else
    return 1.0f / x;
#endif
}
__device__ __forceinline__ float fast_tanh(float x) {
    float t = __expf(2.0f * x);
    return 1.0f - 2.0f * fast_rcp(t + 1.0f);
}
__device__ __forceinline__ float fast_sigmoid(float x) {
    return fast_rcp(1.0f + __expf(-x));
}

// ------ im2col B-stage (64-px, single 32-k' chunk): global->reg, reg->LDS ----
__device__ __forceinline__ uint4 stage_load64(const unsigned short* f2b, int h,
                                              int px0, int chunk, int tid) {
    int tap = chunk >> 1;
    int dh = tap / 3 - 1, dw = tap % 3 - 1;
    int hs = h + dh;
    int kg = tid >> 6, px = tid & 63;       // 256 tasks: kg(4) x px(64)
    int cg = (chunk & 1) * 4 + kg;          // channels cg*8 .. cg*8+7
    int wsrc = px0 + px + dw;
    uint4 pk = {0u, 0u, 0u, 0u};
    if (((unsigned)hs < 128u) && ((unsigned)wsrc < 128u))
        pk = *(const uint4*)(f2b + (((size_t)cg << 14) + (hs << 7) + wsrc) * 8);
    return pk;
}
__device__ __forceinline__ void stage_write64(char* Bst, uint4 pk, int tid) {
    int kg = tid >> 6, px = tid & 63;
    *(uint4*)(Bst + ((kg >> 1) * 2 + (px >> 5)) * 1024
                  + ((px & 31) + 32 * (kg & 1)) * 16) = pk;
}

// -------- k2: merged prep slice + Wcd->LDS + fused 1x1 conv -> fused2 -------
__global__ __launch_bounds__(256, 4)
void k2_fused(const float* __restrict__ x, const float* __restrict__ ref,
              const float* __restrict__ b_cd, const float* __restrict__ w_c,
              const float* __restrict__ w_p, const float* __restrict__ w_m,
              const float* __restrict__ w_conv, const float* __restrict__ w_cd,
              unsigned short* __restrict__ ws) {
    __shared__ __align__(16) char B0[32768];
    __shared__ __align__(16) unsigned short WcdL[8192];
    const int tid = threadIdx.x, l = tid & 63, w = tid >> 6;
    const int b = blockIdx.y, p0 = blockIdx.x * 128;
    const int rl31 = l & 31, kh8 = (l >> 5) * 8;

    // ---- merged prep: grid-stride slice of A_c / A_pm / A_conv repack ----
    {
        int gtid = (blockIdx.y * 128 + blockIdx.x) * 256 + tid;
        #pragma unroll 1
        for (int i = gtid; i < 428032; i += 131072) {
            float val;
            if (i < WS_APM) {               // A_c
                int t = i, jj = t & 7, lx = (t >> 3) & 63, r = t >> 9;
                int ks = r % 36, gmt = r / 36;
                int row = gmt * 32 + (lx & 31);
                int kp = ks * 16 + (lx >> 5) * 8 + jj, tap = kp >> 6, ci = kp & 63;
                val = (row < 576) ? w_c[row * 576 + ci * 9 + tap] : 0.0f;
            } else if (i < WS_ACONV) {      // A_pm
                int t = i - WS_APM, jj = t & 7, lx = (t >> 3) & 63, ks = t >> 9;
                int row = lx & 31;
                int kp = ks * 16 + (lx >> 5) * 8 + jj, tap = kp >> 6, ci = kp & 63;
                val = (row < 18) ? w_p[row * 576 + ci * 9 + tap]
                    : (row < 27) ? w_m[(row - 18) * 576 + ci * 9 + tap] : 0.0f;
            } else {                        // A_conv
                int t = i - WS_ACONV, jj = t & 7, lx = (t >> 3) & 63, r = t >> 9;
                int gks = r % 40, ocT2 = r / 40;
                int oc = ocT2 * 32 + (lx & 31);
                int krow = gks * 16 + (lx >> 5) * 8 + jj;
                val = (krow < 576) ? w_conv[oc * 576 + krow] : 0.0f;
            }
            ws[i] = f2bf(val);
        }
    }
    // ---- Wcd repack -> LDS (row-major [64][128] bf16) ----
    #pragma unroll
    for (int i = tid; i < 8192; i += 256) WcdL[i] = f2bf(w_cd[i]);

    #pragma unroll
    for (int it = 0; it < 8; ++it) {        // 2048 tasks: kg(16) x px(128)
        int task = it * 256 + tid;
        int kg = task >> 7, px = task & 127;
        const float* src = (kg < 8) ? x : ref;
        int kbase = (kg & 7) * 8;
        unsigned short v[8];
        #pragma unroll
        for (int j = 0; j < 8; ++j)
            v[j] = f2bf(src[(((size_t)b * 64 + kbase + j) << 14) + p0 + px]);
        uint4 pk;
        pk.x = (unsigned)v[0] | ((unsigned)v[1] << 16);
        pk.y = (unsigned)v[2] | ((unsigned)v[3] << 16);
        pk.z = (unsigned)v[4] | ((unsigned)v[5] << 16);
        pk.w = (unsigned)v[6] | ((unsigned)v[7] << 16);
        *(uint4*)(B0 + ((kg >> 1) * 4 + (px >> 5)) * 1024
                      + ((px & 31) + 32 * (kg & 1)) * 16) = pk;
    }
    __syncthreads();

    f32x16 a0, a1;
    #pragma unroll
    for (int r = 0; r < 16; ++r) { a0[r] = 0.0f; a1[r] = 0.0f; }
    const unsigned short* A0 = WcdL + rl31 * 128 + kh8;
    #pragma unroll
    for (int s = 0; s < 8; ++s) {
        bf16x8 bf = *(bf16x8*)(B0 + ((s * 4 + w) * 64 + l) * 16);
        bf16x8 x0 = *(const bf16x8*)(A0 + s * 16);
        bf16x8 x1 = *(const bf16x8*)(A0 + 32 * 128 + s * 16);
        a0 = MFMA32(x0, bf, a0);
        a1 = MFMA32(x1, bf, a1);
    }
    unsigned short* f2 = ws + WS_F2 + ((size_t)b << 20);
    int px = p0 + w * 32 + rl31;
    int h4 = (l >> 5) * 4;
    #pragma unroll
    for (int t = 0; t < 2; ++t)
        #pragma unroll
        for (int q = 0; q < 4; ++q) {
            ushort4 st;
            float v0 = (t ? a1[q * 4 + 0] : a0[q * 4 + 0]) + b_cd[t * 32 + 8 * q + h4 + 0];
            float v1 = (t ? a1[q * 4 + 1] : a0[q * 4 + 1]) + b_cd[t * 32 + 8 * q + h4 + 1];
            float v2 = (t ? a1[q * 4 + 2] : a0[q * 4 + 2]) + b_cd[t * 32 + 8 * q + h4 + 2];
            float v3 = (t ? a1[q * 4 + 3] : a0[q * 4 + 3]) + b_cd[t * 32 + 8 * q + h4 + 3];
            st.x = f2bf(v0); st.y = f2bf(v1); st.z = f2bf(v2); st.w = f2bf(v3);
            *(ushort4*)(f2 + ((size_t)((t * 4 + q) << 14) + px) * 8 + h4) = st;
        }
}

// -------- k3: r11 structure, pm folded into pass 0, packed table reads ------
__global__ __launch_bounds__(256, 4)
void k3_main(const float* __restrict__ x, const float* __restrict__ b_c,
             const float* __restrict__ b_p, const float* __restrict__ b_m,
             const unsigned short* __restrict__ wsbf, float* __restrict__ out) {
    __shared__ __align__(16) char lds[36096];
    char* Bst0 = lds;
    char* Bst1 = lds + 4096;
    char* Amod = lds + 8192;
    float* uL = (float*)(lds + 8192);       // 6.9K overlay; dead after tables
    char* tbl = lds + 24576;                // 576 x 16B records
    float* bcL = (float*)(lds + 33792);

    const int tid = threadIdx.x, l = tid & 63, w = tid >> 6;   // 4 waves
    const int lh = l >> 5, l31 = l & 31;
    // XCD-banded decode: xcd = id&7 owns h band [xcd*16, xcd*16+16) x b x half
    const int id = blockIdx.x;
    const int hbLin = (id & 7) * 128 + (id >> 3);
    const int half = hbLin & 1, b = (hbLin >> 1) & 3, h = hbLin >> 3;
    const int px0 = half * 64;
    const unsigned short* f2b = wsbf + WS_F2 + ((size_t)b << 20);
    const float* xb = x + (((size_t)b * 64) << 14);
    const int ocT = w >> 1, nT2 = w & 1;

    for (int i = tid; i < 576; i += 256) bcL[i] = b_c[i];

    f32x16 oa;                              // init deferred to end of pass 0

    // ---- shared epilogue: tanh + packed-table bilinear + modulate ----
    auto epi = [&](f32x16& a, int j, int rowbase) {
        const int pxe = j * 32 + l31;
        if (rowbase < 576) {
            #pragma unroll
            for (int reg = 0; reg < 16; ++reg) {
                int rl = (reg & 3) + 8 * (reg >> 2) + 4 * lh;
                int row = rowbase + rl;
                int c = row / 9, n = row - c * 9;
                float uv = a[reg] + bcL[row];
                float t = fast_tanh(uv);
                uint4 rec = *(const uint4*)(tbl + (pxe * 9 + n) * 16);
                float w0 = __half2float(__ushort_as_half((unsigned short)(rec.x & 0xffffu)));
                float w1 = __half2float(__ushort_as_half((unsigned short)(rec.x >> 16)));
                float w2 = __half2float(__ushort_as_half((unsigned short)(rec.y & 0xffffu)));
                float w3 = __half2float(__ushort_as_half((unsigned short)(rec.y >> 16)));
                int i0 = (int)(rec.z & 0xffffu);
                int i1 = (int)(rec.z >> 16);
                float mval = __uint_as_float(rec.w);
                const float* xp = xb + ((size_t)c << 14);
                f2pair v0 = *(const f2pair*)(xp + i0);
                f2pair v1 = *(const f2pair*)(xp + i1);
                float samp = w0 * v0.x + w1 * v0.y + w2 * v1.x + w3 * v1.y;
                a[reg] = mval * (samp + t);
                // bound gather clustering: <=8 loads in flight
                if ((reg & 3) == 3) __builtin_amdgcn_sched_barrier(0);
            }
        } else {
            #pragma unroll
            for (int reg = 0; reg < 16; ++reg) a[reg] = 0.0f;
        }
    };
    auto scat = [&](const f32x16& a, int j) {
        #pragma unroll
        for (int reg = 0; reg < 16; ++reg) {
            int rl = (reg & 3) + 8 * (reg >> 2) + 4 * lh;
            int k = w * 32 + rl;            // pass-local row in [0,128)
            *(unsigned short*)(Amod + ((k >> 4) * 2 + j) * 1024
                    + (l31 + 32 * ((k >> 3) & 1)) * 16 + (k & 7) * 2)
                = f2bf(a[reg]);
        }
    };

    // ================= pass 0 (mt = w): U-GEMM + pm free-ride ===============
    {
        f32x16 acc0, acc1, pm;
        #pragma unroll
        for (int r = 0; r < 16; ++r) { acc0[r] = 0.0f; acc1[r] = 0.0f; pm[r] = 0.0f; }
        stage_write64(Bst0, stage_load64(f2b, h, px0, 0, tid), tid);
        __syncthreads();
        #pragma unroll 1
        for (int it = 0; it < 18; ++it) {
            char* cur = (it & 1) ? Bst1 : Bst0;
            char* nxt = (it & 1) ? Bst0 : Bst1;
            uint4 pk;
            if (it < 17) pk = stage_load64(f2b, h, px0, it + 1, tid);
            #pragma unroll
            for (int s = 0; s < 2; ++s) {
                const int ks = it * 2 + s;
                bf16x8 bf0 = *(bf16x8*)(cur + ((s * 2 + 0) * 64 + l) * 16);
                bf16x8 bf1 = *(bf16x8*)(cur + ((s * 2 + 1) * 64 + l) * 16);
                bf16x8 af = *(const bf16x8*)(wsbf + WS_AC
                                + (((w * 36 + ks) * 64 + l) << 3));
                acc0 = MFMA32(af, bf0, acc0);
                acc1 = MFMA32(af, bf1, acc1);
                if (w < 2) {                // pm free-ride: wave0->bf0, wave1->bf1
                    bf16x8 apm = *(const bf16x8*)(wsbf + WS_APM + ((ks * 64 + l) << 3));
                    pm = MFMA32(apm, w ? bf1 : bf0, pm);
                }
            }
            if (it < 17) stage_write64(nxt, pk, tid);
            __syncthreads();
        }
        if (w < 2) {                        // pm -> uL (f32); wave w = px block w
            int pxp = w * 32 + l31;
            #pragma unroll
            for (int reg = 0; reg < 16; ++reg) {
                int rl = (reg & 3) + 8 * (reg >> 2) + 4 * lh;
                uL[rl * 64 + pxp] = pm[reg];
            }
        }
        __syncthreads();

        // ---- tables from uL: pair-based bilinear -> packed 16B records ----
        #pragma unroll 1
        for (int i = tid; i < 576; i += 256) {
            int n = i >> 6, px = i & 63;
            float offr = uL[n * 64 + px] + b_p[n];
            float offc = uL[(9 + n) * 64 + px] + b_p[9 + n];
            float mraw = uL[(18 + n) * 64 + px] + b_m[n];
            int nr = n / 3, nc = n - nr * 3;
            float pr = (float)(h + nr) + offr;
            float pc = (float)(px0 + px + nc) + offc;
            float flr = floorf(pr), flc = floorf(pc);
            float prc = fminf(fmaxf(pr, 0.0f), 129.0f);
            float pcc = fminf(fmaxf(pc, 0.0f), 129.0f);
            float q0r = fminf(fmaxf(flr, 0.0f), 129.0f);
            float q1r = fminf(fmaxf(flr + 1.0f, 0.0f), 129.0f);
            int ir0 = (int)q0r, ir1 = (int)q1r;
            bool vr0 = (ir0 >= 1) && (ir0 <= 128), vr1 = (ir1 >= 1) && (ir1 <= 128);
            float wr0 = vr0 ? (1.0f + q0r - prc) : 0.0f;
            float wr1 = vr1 ? (1.0f - (q1r - prc)) : 0.0f;
            float q0c = fminf(fmaxf(flc, 0.0f), 129.0f);
            float q1c = fminf(fmaxf(flc + 1.0f, 0.0f), 129.0f);
            int ic0 = (int)q0c, ic1 = (int)q1c;
            bool vc0 = (ic0 >= 1) && (ic0 <= 128), vc1 = (ic1 >= 1) && (ic1 <= 128);
            float wc0 = vc0 ? (1.0f + q0c - pcc) : 0.0f;
            float wc1 = vc1 ? (1.0f - (q1c - pcc)) : 0.0f;
            int cx0 = ic0 - 1, cx1 = ic1 - 1;
            int base = min(max(cx0, 0), 126);
            float ws0 = ((base == cx0) && vc0 ? wc0 : 0.0f)
                      + ((base == cx1) && vc1 ? wc1 : 0.0f);
            float ws1 = ((base + 1 == cx0) && vc0 ? wc0 : 0.0f)
                      + ((base + 1 == cx1) && vc1 ? wc1 : 0.0f);
            int rx0 = min(max(ir0 - 1, 0), 127), rx1 = min(max(ir1 - 1, 0), 127);
            uint4 rec;
            rec.x = (unsigned)__half_as_ushort(__float2half(wr0 * ws0))
                  | ((unsigned)__half_as_ushort(__float2half(wr0 * ws1)) << 16);
            rec.y = (unsigned)__half_as_ushort(__float2half(wr1 * ws0))
                  | ((unsigned)__half_as_ushort(__float2half(wr1 * ws1)) << 16);
            rec.z = (unsigned)(unsigned short)(rx0 * 128 + base)
                  | ((unsigned)(unsigned short)(rx1 * 128 + base) << 16);
            rec.w = __float_as_uint(fast_sigmoid(mraw));
            *(uint4*)(tbl + (px * 9 + n) * 16) = rec;
        }
        __syncthreads();

        // ---- pass-0 epilogue + out-GEMM (oa initialized here) ----
        epi(acc0, 0, w * 32);
        epi(acc1, 1, w * 32);
        #pragma unroll
        for (int r = 0; r < 16; ++r) oa[r] = 0.0f;
        scat(acc0, 0);
        scat(acc1, 1);
        __syncthreads();
        #pragma unroll
        for (int ks8 = 0; ks8 < 8; ++ks8) {
            bf16x8 af = *(const bf16x8*)(wsbf + WS_ACONV
                            + (((ocT * 40 + ks8) * 64 + l) << 3));
            bf16x8 bf = *(bf16x8*)(Amod + (ks8 * 2 + nT2) * 1024 + l * 16);
            oa = MFMA32(af, bf, oa);
        }
    }

    // ================= passes 1..4 =================
    #pragma unroll 1
    for (int p = 1; p < 5; ++p) {
        const int mt = p * 4 + w;
        f32x16 acc0, acc1;
        #pragma unroll
        for (int r = 0; r < 16; ++r) { acc0[r] = 0.0f; acc1[r] = 0.0f; }

        stage_write64(Bst0, stage_load64(f2b, h, px0, 0, tid), tid);
        __syncthreads();
        #pragma unroll 1
        for (int it = 0; it < 18; ++it) {
            char* cur = (it & 1) ? Bst1 : Bst0;
            char* nxt = (it & 1) ? Bst0 : Bst1;
            uint4 pk;
            if (it < 17) pk = stage_load64(f2b, h, px0, it + 1, tid);
            #pragma unroll
            for (int s = 0; s < 2; ++s) {
                const int ks = it * 2 + s;
                bf16x8 bf0 = *(bf16x8*)(cur + ((s * 2 + 0) * 64 + l) * 16);
                bf16x8 bf1 = *(bf16x8*)(cur + ((s * 2 + 1) * 64 + l) * 16);
                bf16x8 af = *(const bf16x8*)(wsbf + WS_AC
                                + (((mt * 36 + ks) * 64 + l) << 3));
                acc0 = MFMA32(af, bf0, acc0);
                acc1 = MFMA32(af, bf1, acc1);
            }
            if (it < 17) stage_write64(nxt, pk, tid);
            __syncthreads();
        }

        epi(acc0, 0, mt * 32);
        epi(acc1, 1, mt * 32);

        __syncthreads();                    // prev pass's out-GEMM Amod reads done
        scat(acc0, 0);
        scat(acc1, 1);
        __syncthreads();
        #pragma unroll
        for (int ks8 = 0; ks8 < 8; ++ks8) {
            bf16x8 af = *(const bf16x8*)(wsbf + WS_ACONV
                            + (((ocT * 40 + p * 8 + ks8) * 64 + l) << 3));
            bf16x8 bf = *(bf16x8*)(Amod + (ks8 * 2 + nT2) * 1024 + l * 16);
            oa = MFMA32(af, bf, oa);
        }
    }

    // ---- final store: each out element written exactly once ----
    float* ob = out + (((size_t)b * 64) << 14) + (h << 7) + px0 + nT2 * 32 + l31;
    #pragma unroll
    for (int reg = 0; reg < 16; ++reg) {
        int rl = (reg & 3) + 8 * (reg >> 2) + 4 * lh;
        int oc = ocT * 32 + rl;
        ob[(size_t)oc << 14] = oa[reg];
    }
}

extern "C" void kernel_launch(void* const* d_in, const int* in_sizes, int n_in,
                              void* d_out, int out_size, void* d_ws, size_t ws_size,
                              hipStream_t stream) {
    const float* x      = (const float*)d_in[0];
    const float* ref    = (const float*)d_in[1];
    const float* w_cd   = (const float*)d_in[2];
    const float* b_cd   = (const float*)d_in[3];
    const float* w_p    = (const float*)d_in[4];
    const float* b_p    = (const float*)d_in[5];
    const float* w_m    = (const float*)d_in[6];
    const float* b_m    = (const float*)d_in[7];
    const float* w_c    = (const float*)d_in[8];
    const float* b_c    = (const float*)d_in[9];
    const float* w_conv = (const float*)d_in[10];
    float* out = (float*)d_out;
    unsigned short* wsbf = (unsigned short*)d_ws;

    hipLaunchKernelGGL(k2_fused, dim3(128, 4), dim3(256), 0, stream,
                       x, ref, b_cd, w_c, w_p, w_m, w_conv, w_cd, wsbf);
    hipLaunchKernelGGL(k3_main, dim3(1024), dim3(256), 0, stream,
                       x, b_c, b_p, b_m, wsbf, out);
}